// Round 10
// baseline (229.134 us; speedup 1.0000x reference)
//
#include <hip/hip_runtime.h>
#include <hip/hip_bf16.h>
#include <stdint.h>

#define NN 8192
#define FIN 512
#define FOUT 256
#define ALPHAV 0.2f
#define MASKF 9e-15f
#define L2E 1.44269504088896340736f

typedef __attribute__((ext_vector_type(8))) short bf16x8;
typedef __attribute__((ext_vector_type(16))) float f32x16;

static __device__ __forceinline__ float ex2(float x){
#if __has_builtin(__builtin_amdgcn_exp2f)
  return __builtin_amdgcn_exp2f(x);
#else
  return exp2f(x);
#endif
}
static __device__ __forceinline__ unsigned short f2bf(float f){
  __bf16 b = (__bf16)f;
  return __builtin_bit_cast(unsigned short, b);
}

// ---------------- K1: hTt(bf16, granule-tiled) = (x@W)^T, fused f1/f2 -----
// hTt layout: [ktile=j/32][g=(j&31)/8][col][j&7] — 16 KB per ktile.
__global__ __launch_bounds__(256, 2) void k_gemm_h(
    const float* __restrict__ x, const float* __restrict__ Wm,
    const float* __restrict__ aG, unsigned short* __restrict__ hTt,
    float* __restrict__ f1, float* __restrict__ f2)
{
  __shared__ __align__(16) float Bs[4096];   // 16x256 W tile, staging order
  __shared__ __align__(16) float xs[8192];   // 16 rows x 512 k (32 KB)
  const int t  = threadIdx.x;
  const int rg = t >> 6;
  const int cg = t & 63;
  const int i0 = blockIdx.x * 16;
  const int wk = t >> 4;
  const int wc = (t & 15) * 4;

  {
    const int xr = t >> 7;
    const int xc = (t & 127) * 4;
#pragma unroll
    for (int c = 0; c < 8; ++c) {
      const float* gp = x + (size_t)(i0 + c * 2 + xr) * FIN + xc;
      char* lp = ((char*)xs) + c * 4096 + t * 16;
      __builtin_amdgcn_global_load_lds(
          (const __attribute__((address_space(1))) unsigned int*)gp,
          (__attribute__((address_space(3))) unsigned int*)lp, 16, 0, 0);
    }
  }

  float acc[4][4];
#pragma unroll
  for (int r = 0; r < 4; ++r)
#pragma unroll
    for (int c = 0; c < 4; ++c) acc[r][c] = 0.f;

  float4 wreg[4];
#pragma unroll
  for (int q = 0; q < 4; ++q)
    wreg[q] = *(const float4*)(Wm + (size_t)wk * FOUT + q * 64 + wc);

  for (int k0 = 0; k0 < FIN; k0 += 16) {
    __syncthreads();
#pragma unroll
    for (int q = 0; q < 4; ++q)
      *(float4*)(&Bs[q * 1024 + t * 4]) = wreg[q];
    __syncthreads();
    if (k0 + 16 < FIN) {
#pragma unroll
      for (int q = 0; q < 4; ++q)
        wreg[q] = *(const float4*)(Wm + (size_t)(k0 + 16 + wk) * FOUT + q * 64 + wc);
    }
#pragma unroll
    for (int q = 0; q < 4; ++q) {
      float4 xa[4];
#pragma unroll
      for (int r = 0; r < 4; ++r)
        xa[r] = *(const float4*)(&xs[(rg * 4 + r) * 512 + k0 + q * 4]);
#pragma unroll
      for (int k2 = 0; k2 < 4; ++k2) {
        const int kk = q * 4 + k2;
        float4 bv = *(const float4*)(&Bs[(cg >> 4) * 1024 + kk * 64 + (cg & 15) * 4]);
        float bb4[4] = {bv.x, bv.y, bv.z, bv.w};
#pragma unroll
        for (int r = 0; r < 4; ++r) {
          float ar = (k2 == 0) ? xa[r].x : (k2 == 1) ? xa[r].y : (k2 == 2) ? xa[r].z : xa[r].w;
#pragma unroll
          for (int c = 0; c < 4; ++c) acc[r][c] = fmaf(ar, bb4[c], acc[r][c]);
        }
      }
    }
  }
  const int j0  = i0 + rg * 4;
  const int kt  = j0 >> 5;
  const int jin = j0 & 31;
  const size_t sbase = (size_t)kt * 8192 + (size_t)(jin >> 3) * 2048 + (jin & 7);
#pragma unroll
  for (int c = 0; c < 4; ++c) {
    int col = cg * 4 + c;
    ushort4 u;
    u.x = f2bf(acc[0][c]); u.y = f2bf(acc[1][c]);
    u.z = f2bf(acc[2][c]); u.w = f2bf(acc[3][c]);
    *(ushort4*)(hTt + sbase + col * 8) = u;
  }
  float4 a1 = *(const float4*)(aG + cg * 4);
  float4 a2 = *(const float4*)(aG + FOUT + cg * 4);
#pragma unroll
  for (int r = 0; r < 4; ++r) {
    float s1 = acc[r][0]*a1.x + acc[r][1]*a1.y + acc[r][2]*a1.z + acc[r][3]*a1.w;
    float s2 = acc[r][0]*a2.x + acc[r][1]*a2.y + acc[r][2]*a2.z + acc[r][3]*a2.w;
#pragma unroll
    for (int off = 32; off > 0; off >>= 1) {
      s1 += __shfl_xor(s1, off);
      s2 += __shfl_xor(s2, off);
    }
    if (cg == 0) { f1[i0 + rg * 4 + r] = s1; f2[i0 + rg * 4 + r] = s2; }
  }
}

// ---------------- K2: row-max UPPER BOUND m̂_i = lrelu(f1_i + max f2) ------
__global__ __launch_bounds__(1024) void k_bound(
    const float* __restrict__ f1, const float* __restrict__ f2,
    float* __restrict__ mhat)
{
  __shared__ float red[16];
  const int t = threadIdx.x;
  float m = -3.0e38f;
#pragma unroll
  for (int k = 0; k < 8; ++k) m = fmaxf(m, f2[t + k * 1024]);
#pragma unroll
  for (int off = 32; off > 0; off >>= 1) m = fmaxf(m, __shfl_xor(m, off));
  if ((t & 63) == 0) red[t >> 6] = m;
  __syncthreads();
  float fm = red[0];
#pragma unroll
  for (int w = 1; w < 16; ++w) fm = fmaxf(fm, red[w]);
#pragma unroll
  for (int k = 0; k < 8; ++k) {
    int i = t + k * 1024;
    float s = f1[i] + fm;
    mhat[i] = fmaxf(fmaxf(s, ALPHAV * s), MASKF);
  }
}

// ---------------- K2b: adj -> tiled bitmask, ONE coalesced stream ---------
// maskT layout: u32 at [(bx*8+ks)*32 + jt][row 0..127] — each block's
// (128 rows x 1024 j) tile is 16 KB CONTIGUOUS for spmm's preload.
// Reads: per pass, each lane reads 128 B of one row; block streams
// 128 x 4 KB row-chunks (HBM-sequential). grid (64, 8).
__global__ __launch_bounds__(256) void k_mask(
    const int* __restrict__ adj, unsigned int* __restrict__ maskT)
{
  __shared__ unsigned int mls[32 * 129];   // [jt][row], pad 1 -> conflict-free
  const int t  = threadIdx.x;
  const int bx = blockIdx.x;
  const int ks = blockIdx.y;
  const int jt = t & 31;
  const int r8 = t >> 5;                   // 0..7
  const int* gp = adj + (size_t)(bx * 128 + r8) * NN + ks * 1024 + jt * 32;

#pragma unroll 1
  for (int p = 0; p < 16; ++p) {
    const int* rp = gp + (size_t)p * 8 * NN;
    int4 v[8];
#pragma unroll
    for (int c = 0; c < 8; ++c) v[c] = *(const int4*)(rp + c * 4);
    unsigned int m = 0;
#pragma unroll
    for (int c = 0; c < 8; ++c) {
      m |= (v[c].x > 0 ? 1u : 0u) << (c * 4 + 0);
      m |= (v[c].y > 0 ? 1u : 0u) << (c * 4 + 1);
      m |= (v[c].z > 0 ? 1u : 0u) << (c * 4 + 2);
      m |= (v[c].w > 0 ? 1u : 0u) << (c * 4 + 3);
    }
    mls[jt * 129 + p * 8 + r8] = m;
  }
  __syncthreads();
  unsigned int* outb = maskT + (size_t)(bx * 8 + ks) * 4096;
#pragma unroll
  for (int g = 0; g < 4; ++g) {
    const int L = t * 16 + g * 4;
    uint4 o;
    o.x = mls[((L + 0) >> 7) * 129 + ((L + 0) & 127)];
    o.y = mls[((L + 1) >> 7) * 129 + ((L + 1) & 127)];
    o.z = mls[((L + 2) >> 7) * 129 + ((L + 2) & 127)];
    o.w = mls[((L + 3) >> 7) * 129 + ((L + 3) & 127)];
    *(uint4*)(outb + L) = o;
  }
}

// ---------------- K3: P-regen from bitmask + (P@h) via 32x32x16 MFMA ------
// Wave = 32 rows x full 256 cols. Block = 4 waves (128 rows). grid (64, 8).
// ZERO per-step global reads except the 4 sequential hTt staging loads
// (L2-resident): counted vmcnt(4), 3 LDS bufs, depth-2, one barrier/step.
// Mask tile (16 KB) + f2 slice preloaded once.
__global__ __launch_bounds__(256, 2) void k_spmm(
    const unsigned short* __restrict__ hTt,
    const unsigned int* __restrict__ maskT,
    const float* __restrict__ f1, const float* __restrict__ f2,
    const float* __restrict__ mhat,
    float* __restrict__ part, float* __restrict__ rowsumP)
{
  __shared__ __align__(16) unsigned short hbuf[3 * 8192]; // 3 x 16 KB
  __shared__ __align__(16) unsigned int mskL[4096];       // [jt][row] 16 KB
  __shared__ __align__(16) float f2s[1024];               // pre-scaled by L2E
  const int t  = threadIdx.x;
  const int wv = t >> 6;
  const int l  = t & 63;
  const int lh = l >> 5;           // k-half of lane
  const int lm = l & 31;           // row (A) / col (B) within 32
  const int bx = blockIdx.x;
  const int ks = blockIdx.y;
  const int r0 = bx * 128;
  const int lh8 = lh * 8;

  const int rA = r0 + wv * 32 + lm;
  const float nmA   = -mhat[rA] * L2E;
  const float base0 = fmaf(f1[rA], L2E, nmA);
  const float c20   = nmA * (1.f - ALPHAV);
  const float mc0   = fmaf(MASKF, L2E, nmA);

  // f2 slice -> LDS (pre-scaled). Value-use drains its loads here.
  {
    float4 v = *(const float4*)(f2 + ks * 1024 + t * 4);
    v.x *= L2E; v.y *= L2E; v.z *= L2E; v.w *= L2E;
    *(float4*)(&f2s[t * 4]) = v;
  }
  __builtin_amdgcn_sched_barrier(0);

  f32x16 acc[8];
#pragma unroll
  for (int c = 0; c < 8; ++c)
#pragma unroll
    for (int e = 0; e < 16; ++e) acc[c][e] = 0.f;
  float sumP = 0.f;

  const unsigned short* gt0 = hTt + (size_t)ks * 32 * 8192;
  const char* cbase = (const char*)hbuf;
  const int mrow = wv * 32 + lm;

#define SB0 __builtin_amdgcn_sched_barrier(0)
#define STAGE(BUFI, JT)                                                       \
  do {                                                                        \
    const unsigned short* gp_ = gt0 + (size_t)(JT) * 8192 + t * 8;            \
    char* lp_ = ((char*)hbuf) + (BUFI) * 16384 + t * 16;                      \
    _Pragma("unroll")                                                         \
    for (int c = 0; c < 4; ++c) {                                             \
      __builtin_amdgcn_global_load_lds(                                       \
          (const __attribute__((address_space(1))) unsigned int*)(gp_ + c * 2048), \
          (__attribute__((address_space(3))) unsigned int*)(lp_ + c * 4096),  \
          16, 0, 0);                                                          \
    }                                                                         \
  } while (0)

#define REGEN8(AFR, MB, FB)                                                   \
  do {                                                                        \
    float4 fx_ = *(const float4*)(&f2s[FB]);                                  \
    float4 fy_ = *(const float4*)(&f2s[(FB) + 4]);                            \
    float fv_[8] = {fx_.x, fx_.y, fx_.z, fx_.w, fy_.x, fy_.y, fy_.z, fy_.w};  \
    _Pragma("unroll")                                                         \
    for (int b = 0; b < 8; ++b) {                                             \
      float u_ = base0 + fv_[b];                                              \
      float w_ = fmaxf(u_, fmaf(ALPHAV, u_, c20));                            \
      w_ = (((MB) >> b) & 1u) ? w_ : mc0;                                     \
      float p_ = ex2(w_);                                                     \
      sumP += p_;                                                             \
      AFR[b] = (short)f2bf(p_);                                               \
    }                                                                         \
  } while (0)

#define TS(JT, BUF, NBUF, DOISSUE, VMC)                                       \
  do {                                                                        \
    asm volatile("s_waitcnt vmcnt(" #VMC ")" ::: "memory");                   \
    __builtin_amdgcn_s_barrier();                                             \
    SB0;                                                                      \
    if (DOISSUE) STAGE(NBUF, (JT) + 2);                                       \
    SB0;                                                                      \
    const unsigned int m_ = mskL[(JT) * 128 + mrow];                          \
    bf16x8 afr0_, afr1_;                                                      \
    REGEN8(afr0_, m_ >> lh8,        (JT) * 32 + lh8);                         \
    REGEN8(afr1_, m_ >> (16 + lh8), (JT) * 32 + 16 + lh8);                    \
    SB0;                                                                      \
    const char* lb_ = cbase + (BUF) * 16384;                                  \
    const int g0_ = lh * 4096;                                                \
    const int g1_ = (2 + lh) * 4096;                                          \
    const int cb_ = lm * 16;                                                  \
    _Pragma("unroll")                                                         \
    for (int c = 0; c < 8; ++c) {                                             \
      bf16x8 b0_ = *(const bf16x8*)(lb_ + g0_ + c * 512 + cb_);               \
      acc[c] = __builtin_amdgcn_mfma_f32_32x32x16_bf16(afr0_, b0_, acc[c], 0, 0, 0); \
      bf16x8 b1_ = *(const bf16x8*)(lb_ + g1_ + c * 512 + cb_);               \
      acc[c] = __builtin_amdgcn_mfma_f32_32x32x16_bf16(afr1_, b1_, acc[c], 0, 0, 0); \
    }                                                                         \
  } while (0)

  // prologue counted stream: [mask x4, stage(0) x4, stage(1) x4] = 12 ops
  {
    const unsigned int* mt = maskT + (size_t)(bx * 8 + ks) * 4096;
#pragma unroll
    for (int s = 0; s < 4; ++s) {
      __builtin_amdgcn_global_load_lds(
          (const __attribute__((address_space(1))) unsigned int*)(mt + s * 1024 + t * 4),
          (__attribute__((address_space(3))) unsigned int*)(((char*)mskL) + s * 4096 + t * 16),
          16, 0, 0);
    }
  }
  SB0;
  STAGE(0, 0);
  SB0;
  STAGE(1, 1);
  asm volatile("s_waitcnt lgkmcnt(0)" ::: "memory");  // f2s ds_writes drained
  SB0;

#pragma unroll 1
  for (int p = 0; p < 10; ++p) {
    const int s0 = p * 3;
    TS(s0 + 0, 0, 2, 1, 4);
    TS(s0 + 1, 1, 0, 1, 4);
    TS(s0 + 2, 2, 1, 1, 4);
  }
  TS(30, 0, 2, 0, 4);
  TS(31, 1, 0, 0, 0);

#undef SB0
#undef STAGE
#undef REGEN8
#undef TS

  // rowsum: lanes l and l^32 hold the two k-halves of row lm
  sumP += __shfl_xor(sumP, 32);
  if (lh == 0) rowsumP[(size_t)ks * NN + rA] = sumP;

  // C-write: col = c*32 + lm; row = r0 + wv*32 + 4*lh + (reg&3) + 8*(reg>>2)
  float* dst = part + (size_t)ks * NN * FOUT;
  const int rowb = r0 + wv * 32 + 4 * lh;
#pragma unroll
  for (int c = 0; c < 8; ++c) {
    const int col = c * 32 + lm;
#pragma unroll
    for (int reg = 0; reg < 16; ++reg) {
      int row = rowb + (reg & 3) + 8 * (reg >> 2);
      dst[(size_t)row * FOUT + col] = acc[c][reg];
    }
  }
}

// ---------------- K4: sum 8 K-partials + rowsums, normalize ---------------
__global__ __launch_bounds__(256) void k_fin(
    float* __restrict__ outp, const float* __restrict__ part,
    const float* __restrict__ rowsumP)
{
  const int idx4 = blockIdx.x * 256 + threadIdx.x;
  const size_t e = (size_t)idx4 * 4;
  const int i = (int)(e >> 8);
  float rs = 0.f;
#pragma unroll
  for (int p = 0; p < 8; ++p) rs += rowsumP[(size_t)p * NN + i];
  float4 o = {0.f, 0.f, 0.f, 0.f};
#pragma unroll
  for (int p = 0; p < 8; ++p) {
    float4 pv = *(const float4*)(part + (size_t)p * NN * FOUT + e);
    o.x += pv.x; o.y += pv.y; o.z += pv.z; o.w += pv.w;
  }
  float inv = 1.f / rs;
  o.x *= inv; o.y *= inv; o.z *= inv; o.w *= inv;
  *(float4*)(outp + e) = o;
}

extern "C" void kernel_launch(void* const* d_in, const int* in_sizes, int n_in,
                              void* d_out, int out_size, void* d_ws, size_t ws_size,
                              hipStream_t stream)
{
  const float* x  = (const float*)d_in[0];
  const int* adj  = (const int*)d_in[1];
  const float* Wm = (const float*)d_in[2];
  const float* aG = (const float*)d_in[3];
  float* outp = (float*)d_out;

  char* w = (char*)d_ws;
  unsigned short* hTt = (unsigned short*)(w + 0);            // 4 MB (tiled)
  float* f1           = (float*)(w + 4194304);               // 32 KB
  float* f2           = (float*)(w + 4227072);               // 32 KB
  float* mhat         = (float*)(w + 4259840);               // 32 KB
  float* rowsumP      = (float*)(w + 4292608);               // 256 KB
  unsigned int* maskT = (unsigned int*)(w + 4554752);        // 4 MB (tiled)
  float* part         = (float*)(w + 8749056);               // 64 MB (8 slices)

  hipLaunchKernelGGL(k_gemm_h, dim3(512),   dim3(256),  0, stream, x, Wm, aG, hTt, f1, f2);
  hipLaunchKernelGGL(k_bound,  dim3(1),     dim3(1024), 0, stream, f1, f2, mhat);
  hipLaunchKernelGGL(k_mask,   dim3(64, 8), dim3(256),  0, stream, adj, maskT);
  hipLaunchKernelGGL(k_spmm,   dim3(64, 8), dim3(256),  0, stream, hTt, maskT, f1, f2, mhat, part, rowsumP);
  hipLaunchKernelGGL(k_fin,    dim3(2048),  dim3(256),  0, stream, outp, part, rowsumP);
}

// Round 11
// 191.728 us; speedup vs baseline: 1.1951x; 1.1951x over previous
//
#include <hip/hip_runtime.h>
#include <hip/hip_bf16.h>
#include <stdint.h>

#define NN 8192
#define FIN 512
#define FOUT 256
#define ALPHAV 0.2f
#define MASKF 9e-15f
#define L2E 1.44269504088896340736f

typedef __attribute__((ext_vector_type(8))) short bf16x8;
typedef __attribute__((ext_vector_type(16))) float f32x16;

static __device__ __forceinline__ float ex2(float x){
#if __has_builtin(__builtin_amdgcn_exp2f)
  return __builtin_amdgcn_exp2f(x);
#else
  return exp2f(x);
#endif
}
static __device__ __forceinline__ unsigned short f2bf(float f){
  __bf16 b = (__bf16)f;
  return __builtin_bit_cast(unsigned short, b);
}

// ---------------- K1: hTt(bf16, granule-tiled) = (x@W)^T, fused f1/f2 -----
// hTt layout: [ktile=j/32][g=(j&31)/8][col][j&7] — 16 KB per ktile.
__global__ __launch_bounds__(256, 2) void k_gemm_h(
    const float* __restrict__ x, const float* __restrict__ Wm,
    const float* __restrict__ aG, unsigned short* __restrict__ hTt,
    float* __restrict__ f1, float* __restrict__ f2)
{
  __shared__ __align__(16) float Bs[4096];   // 16x256 W tile, staging order
  __shared__ __align__(16) float xs[8192];   // 16 rows x 512 k (32 KB)
  const int t  = threadIdx.x;
  const int rg = t >> 6;
  const int cg = t & 63;
  const int i0 = blockIdx.x * 16;
  const int wk = t >> 4;
  const int wc = (t & 15) * 4;

  {
    const int xr = t >> 7;
    const int xc = (t & 127) * 4;
#pragma unroll
    for (int c = 0; c < 8; ++c) {
      const float* gp = x + (size_t)(i0 + c * 2 + xr) * FIN + xc;
      char* lp = ((char*)xs) + c * 4096 + t * 16;
      __builtin_amdgcn_global_load_lds(
          (const __attribute__((address_space(1))) unsigned int*)gp,
          (__attribute__((address_space(3))) unsigned int*)lp, 16, 0, 0);
    }
  }

  float acc[4][4];
#pragma unroll
  for (int r = 0; r < 4; ++r)
#pragma unroll
    for (int c = 0; c < 4; ++c) acc[r][c] = 0.f;

  float4 wreg[4];
#pragma unroll
  for (int q = 0; q < 4; ++q)
    wreg[q] = *(const float4*)(Wm + (size_t)wk * FOUT + q * 64 + wc);

  for (int k0 = 0; k0 < FIN; k0 += 16) {
    __syncthreads();
#pragma unroll
    for (int q = 0; q < 4; ++q)
      *(float4*)(&Bs[q * 1024 + t * 4]) = wreg[q];
    __syncthreads();
    if (k0 + 16 < FIN) {
#pragma unroll
      for (int q = 0; q < 4; ++q)
        wreg[q] = *(const float4*)(Wm + (size_t)(k0 + 16 + wk) * FOUT + q * 64 + wc);
    }
#pragma unroll
    for (int q = 0; q < 4; ++q) {
      float4 xa[4];
#pragma unroll
      for (int r = 0; r < 4; ++r)
        xa[r] = *(const float4*)(&xs[(rg * 4 + r) * 512 + k0 + q * 4]);
#pragma unroll
      for (int k2 = 0; k2 < 4; ++k2) {
        const int kk = q * 4 + k2;
        float4 bv = *(const float4*)(&Bs[(cg >> 4) * 1024 + kk * 64 + (cg & 15) * 4]);
        float bb4[4] = {bv.x, bv.y, bv.z, bv.w};
#pragma unroll
        for (int r = 0; r < 4; ++r) {
          float ar = (k2 == 0) ? xa[r].x : (k2 == 1) ? xa[r].y : (k2 == 2) ? xa[r].z : xa[r].w;
#pragma unroll
          for (int c = 0; c < 4; ++c) acc[r][c] = fmaf(ar, bb4[c], acc[r][c]);
        }
      }
    }
  }
  const int j0  = i0 + rg * 4;
  const int kt  = j0 >> 5;
  const int jin = j0 & 31;
  const size_t sbase = (size_t)kt * 8192 + (size_t)(jin >> 3) * 2048 + (jin & 7);
#pragma unroll
  for (int c = 0; c < 4; ++c) {
    int col = cg * 4 + c;
    ushort4 u;
    u.x = f2bf(acc[0][c]); u.y = f2bf(acc[1][c]);
    u.z = f2bf(acc[2][c]); u.w = f2bf(acc[3][c]);
    *(ushort4*)(hTt + sbase + col * 8) = u;
  }
  float4 a1 = *(const float4*)(aG + cg * 4);
  float4 a2 = *(const float4*)(aG + FOUT + cg * 4);
#pragma unroll
  for (int r = 0; r < 4; ++r) {
    float s1 = acc[r][0]*a1.x + acc[r][1]*a1.y + acc[r][2]*a1.z + acc[r][3]*a1.w;
    float s2 = acc[r][0]*a2.x + acc[r][1]*a2.y + acc[r][2]*a2.z + acc[r][3]*a2.w;
#pragma unroll
    for (int off = 32; off > 0; off >>= 1) {
      s1 += __shfl_xor(s1, off);
      s2 += __shfl_xor(s2, off);
    }
    if (cg == 0) { f1[i0 + rg * 4 + r] = s1; f2[i0 + rg * 4 + r] = s2; }
  }
}

// ---------------- K2: row-max UPPER BOUND m̂_i = lrelu(f1_i + max f2) ------
__global__ __launch_bounds__(1024) void k_bound(
    const float* __restrict__ f1, const float* __restrict__ f2,
    float* __restrict__ mhat)
{
  __shared__ float red[16];
  const int t = threadIdx.x;
  float m = -3.0e38f;
#pragma unroll
  for (int k = 0; k < 8; ++k) m = fmaxf(m, f2[t + k * 1024]);
#pragma unroll
  for (int off = 32; off > 0; off >>= 1) m = fmaxf(m, __shfl_xor(m, off));
  if ((t & 63) == 0) red[t >> 6] = m;
  __syncthreads();
  float fm = red[0];
#pragma unroll
  for (int w = 1; w < 16; ++w) fm = fmaxf(fm, red[w]);
#pragma unroll
  for (int k = 0; k < 8; ++k) {
    int i = t + k * 1024;
    float s = f1[i] + fm;
    mhat[i] = fmaxf(fmaxf(s, ALPHAV * s), MASKF);
  }
}

// ---------------- K3: FUSED adj->bitmask + P-regen + (P@h) MFMA -----------
// Prologue: block converts its own 128x1024 adj tile to an LDS bitmask
// (coalesced 4 KB row-chunks — same pattern as the R10 k_mask). With 2
// blocks/CU, one block's HBM-bound prologue overlaps the other's compute.
// Main loop identical to R10: 3 LDS bufs, counted vmcnt(4), 1 barrier/step.
// grid (64, 8), 4 waves, wave = 32 rows x full 256 cols.
__global__ __launch_bounds__(256, 2) void k_spmm(
    const unsigned short* __restrict__ hTt,
    const int* __restrict__ adj,
    const float* __restrict__ f1, const float* __restrict__ f2,
    const float* __restrict__ mhat,
    float* __restrict__ part, float* __restrict__ rowsumP)
{
  __shared__ __align__(16) unsigned short hbuf[3 * 8192]; // 3 x 16 KB
  __shared__ __align__(16) unsigned int mskL[32 * 129];   // [jt][row]+pad 16.5 KB
  __shared__ __align__(16) float f2s[1024];               // pre-scaled by L2E
  const int t  = threadIdx.x;
  const int wv = t >> 6;
  const int l  = t & 63;
  const int lh = l >> 5;           // k-half of lane
  const int lm = l & 31;           // row (A) / col (B) within 32
  const int bx = blockIdx.x;
  const int ks = blockIdx.y;
  const int r0 = bx * 128;
  const int lh8 = lh * 8;

  const int rA = r0 + wv * 32 + lm;
  const float nmA   = -mhat[rA] * L2E;
  const float base0 = fmaf(f1[rA], L2E, nmA);
  const float c20   = nmA * (1.f - ALPHAV);
  const float mc0   = fmaf(MASKF, L2E, nmA);

  // f2 slice -> LDS (pre-scaled)
  {
    float4 v = *(const float4*)(f2 + ks * 1024 + t * 4);
    v.x *= L2E; v.y *= L2E; v.z *= L2E; v.w *= L2E;
    *(float4*)(&f2s[t * 4]) = v;
  }

  // ---- prologue: adj(128 rows x 1024 j) -> mskL, coalesced row-chunks ----
  {
    const int jt = t & 31;          // j-chunk (32 ints = 128 B)
    const int r8 = t >> 5;          // 0..7
    const int* gp = adj + (size_t)(r0 + r8) * NN + ks * 1024 + jt * 32;
#pragma unroll 2
    for (int p = 0; p < 16; ++p) {
      const int* rp = gp + (size_t)p * 8 * NN;
      int4 v[8];
#pragma unroll
      for (int c = 0; c < 8; ++c) v[c] = *(const int4*)(rp + c * 4);
      unsigned int m = 0;
#pragma unroll
      for (int c = 0; c < 8; ++c) {
        m |= (v[c].x > 0 ? 1u : 0u) << (c * 4 + 0);
        m |= (v[c].y > 0 ? 1u : 0u) << (c * 4 + 1);
        m |= (v[c].z > 0 ? 1u : 0u) << (c * 4 + 2);
        m |= (v[c].w > 0 ? 1u : 0u) << (c * 4 + 3);
      }
      mskL[jt * 129 + p * 8 + r8] = m;
    }
  }
  __builtin_amdgcn_sched_barrier(0);

  f32x16 acc[8];
#pragma unroll
  for (int c = 0; c < 8; ++c)
#pragma unroll
    for (int e = 0; e < 16; ++e) acc[c][e] = 0.f;
  float sumP = 0.f;

  const unsigned short* gt0 = hTt + (size_t)ks * 32 * 8192;
  const char* cbase = (const char*)hbuf;
  const int mrow = wv * 32 + lm;

#define SB0 __builtin_amdgcn_sched_barrier(0)
#define STAGE(BUFI, JT)                                                       \
  do {                                                                        \
    const unsigned short* gp_ = gt0 + (size_t)(JT) * 8192 + t * 8;            \
    char* lp_ = ((char*)hbuf) + (BUFI) * 16384 + t * 16;                      \
    _Pragma("unroll")                                                         \
    for (int c = 0; c < 4; ++c) {                                             \
      __builtin_amdgcn_global_load_lds(                                       \
          (const __attribute__((address_space(1))) unsigned int*)(gp_ + c * 2048), \
          (__attribute__((address_space(3))) unsigned int*)(lp_ + c * 4096),  \
          16, 0, 0);                                                          \
    }                                                                         \
  } while (0)

#define REGEN8(AFR, MB, FB)                                                   \
  do {                                                                        \
    float4 fx_ = *(const float4*)(&f2s[FB]);                                  \
    float4 fy_ = *(const float4*)(&f2s[(FB) + 4]);                            \
    float fv_[8] = {fx_.x, fx_.y, fx_.z, fx_.w, fy_.x, fy_.y, fy_.z, fy_.w};  \
    _Pragma("unroll")                                                         \
    for (int b = 0; b < 8; ++b) {                                             \
      float u_ = base0 + fv_[b];                                              \
      float w_ = fmaxf(u_, fmaf(ALPHAV, u_, c20));                            \
      w_ = (((MB) >> b) & 1u) ? w_ : mc0;                                     \
      float p_ = ex2(w_);                                                     \
      sumP += p_;                                                             \
      AFR[b] = (short)f2bf(p_);                                               \
    }                                                                         \
  } while (0)

#define TS(JT, BUF, NBUF, DOISSUE, VMC)                                       \
  do {                                                                        \
    asm volatile("s_waitcnt vmcnt(" #VMC ")" ::: "memory");                   \
    __builtin_amdgcn_s_barrier();                                             \
    SB0;                                                                      \
    if (DOISSUE) STAGE(NBUF, (JT) + 2);                                       \
    SB0;                                                                      \
    const unsigned int m_ = mskL[(JT) * 129 + mrow];                          \
    bf16x8 afr0_, afr1_;                                                      \
    REGEN8(afr0_, m_ >> lh8,        (JT) * 32 + lh8);                         \
    REGEN8(afr1_, m_ >> (16 + lh8), (JT) * 32 + 16 + lh8);                    \
    SB0;                                                                      \
    const char* lb_ = cbase + (BUF) * 16384;                                  \
    const int g0_ = lh * 4096;                                                \
    const int g1_ = (2 + lh) * 4096;                                          \
    const int cb_ = lm * 16;                                                  \
    _Pragma("unroll")                                                         \
    for (int c = 0; c < 8; ++c) {                                             \
      bf16x8 b0_ = *(const bf16x8*)(lb_ + g0_ + c * 512 + cb_);               \
      acc[c] = __builtin_amdgcn_mfma_f32_32x32x16_bf16(afr0_, b0_, acc[c], 0, 0, 0); \
      bf16x8 b1_ = *(const bf16x8*)(lb_ + g1_ + c * 512 + cb_);               \
      acc[c] = __builtin_amdgcn_mfma_f32_32x32x16_bf16(afr1_, b1_, acc[c], 0, 0, 0); \
    }                                                                         \
  } while (0)

  // prologue counted stream: [stage(0) x4, stage(1) x4] = 8 vmem ops
  STAGE(0, 0);
  SB0;
  STAGE(1, 1);
  asm volatile("s_waitcnt lgkmcnt(0)" ::: "memory");  // f2s + mskL ds_writes
  SB0;
  // (first TS's barrier makes mskL/f2s visible to all waves)

#pragma unroll 1
  for (int p = 0; p < 10; ++p) {
    const int s0 = p * 3;
    TS(s0 + 0, 0, 2, 1, 4);
    TS(s0 + 1, 1, 0, 1, 4);
    TS(s0 + 2, 2, 1, 1, 4);
  }
  TS(30, 0, 2, 0, 4);
  TS(31, 1, 0, 0, 0);

#undef SB0
#undef STAGE
#undef REGEN8
#undef TS

  // rowsum: lanes l and l^32 hold the two k-halves of row lm
  sumP += __shfl_xor(sumP, 32);
  if (lh == 0) rowsumP[(size_t)ks * NN + rA] = sumP;

  // C-write: col = c*32 + lm; row = r0 + wv*32 + 4*lh + (reg&3) + 8*(reg>>2)
  float* dst = part + (size_t)ks * NN * FOUT;
  const int rowb = r0 + wv * 32 + 4 * lh;
#pragma unroll
  for (int c = 0; c < 8; ++c) {
    const int col = c * 32 + lm;
#pragma unroll
    for (int reg = 0; reg < 16; ++reg) {
      int row = rowb + (reg & 3) + 8 * (reg >> 2);
      dst[(size_t)row * FOUT + col] = acc[c][reg];
    }
  }
}

// ---------------- K4: sum 8 K-partials + rowsums, normalize ---------------
__global__ __launch_bounds__(256) void k_fin(
    float* __restrict__ outp, const float* __restrict__ part,
    const float* __restrict__ rowsumP)
{
  const int idx4 = blockIdx.x * 256 + threadIdx.x;
  const size_t e = (size_t)idx4 * 4;
  const int i = (int)(e >> 8);
  float rs = 0.f;
#pragma unroll
  for (int p = 0; p < 8; ++p) rs += rowsumP[(size_t)p * NN + i];
  float4 o = {0.f, 0.f, 0.f, 0.f};
#pragma unroll
  for (int p = 0; p < 8; ++p) {
    float4 pv = *(const float4*)(part + (size_t)p * NN * FOUT + e);
    o.x += pv.x; o.y += pv.y; o.z += pv.z; o.w += pv.w;
  }
  float inv = 1.f / rs;
  o.x *= inv; o.y *= inv; o.z *= inv; o.w *= inv;
  *(float4*)(outp + e) = o;
}

extern "C" void kernel_launch(void* const* d_in, const int* in_sizes, int n_in,
                              void* d_out, int out_size, void* d_ws, size_t ws_size,
                              hipStream_t stream)
{
  const float* x  = (const float*)d_in[0];
  const int* adj  = (const int*)d_in[1];
  const float* Wm = (const float*)d_in[2];
  const float* aG = (const float*)d_in[3];
  float* outp = (float*)d_out;

  char* w = (char*)d_ws;
  unsigned short* hTt = (unsigned short*)(w + 0);            // 4 MB (tiled)
  float* f1           = (float*)(w + 4194304);               // 32 KB
  float* f2           = (float*)(w + 4227072);               // 32 KB
  float* mhat         = (float*)(w + 4259840);               // 32 KB
  float* rowsumP      = (float*)(w + 4292608);               // 256 KB
  float* part         = (float*)(w + 4554752);               // 64 MB (8 slices)

  hipLaunchKernelGGL(k_gemm_h, dim3(512),   dim3(256),  0, stream, x, Wm, aG, hTt, f1, f2);
  hipLaunchKernelGGL(k_bound,  dim3(1),     dim3(1024), 0, stream, f1, f2, mhat);
  hipLaunchKernelGGL(k_spmm,   dim3(64, 8), dim3(256),  0, stream, hTt, adj, f1, f2, mhat, part, rowsumP);
  hipLaunchKernelGGL(k_fin,    dim3(2048),  dim3(256),  0, stream, outp, part, rowsumP);
}

// Round 12
// 137.789 us; speedup vs baseline: 1.6629x; 1.3915x over previous
//
#include <hip/hip_runtime.h>
#include <hip/hip_bf16.h>
#include <stdint.h>

#define NN 8192
#define FIN 512
#define FOUT 256
#define ALPHAV 0.2f
#define MASKF 9e-15f
#define L2E 1.44269504088896340736f

typedef __attribute__((ext_vector_type(8))) short bf16x8;
typedef __attribute__((ext_vector_type(16))) float f32x16;

static __device__ __forceinline__ float ex2(float x){
#if __has_builtin(__builtin_amdgcn_exp2f)
  return __builtin_amdgcn_exp2f(x);
#else
  return exp2f(x);
#endif
}
static __device__ __forceinline__ unsigned short f2bf(float f){
  __bf16 b = (__bf16)f;
  return __builtin_bit_cast(unsigned short, b);
}
static __device__ __forceinline__ float bf2f(unsigned short u){
  unsigned int v = ((unsigned int)u) << 16;
  return __builtin_bit_cast(float, v);
}

// ---------------- K0: W(512x256 f32) -> Wt hi/lo, step-tiled bf16 ---------
// Wt layout: [kstep=k/16][kg=(k&15)/8][n][k&7] — per-step 8 KB chunk is the
// EXACT LDS image the gemm stages (linear global_load_lds copy).
__global__ __launch_bounds__(256) void k_prep(
    const float* __restrict__ Wm, unsigned short* __restrict__ WtHi,
    unsigned short* __restrict__ WtLo)
{
  __shared__ float ls[16 * 256];
  const int t = threadIdx.x;
  const int S = blockIdx.x;          // kstep 0..31
  const int k0 = S * 16;
  {
    const int kk = t >> 4;
    const int n0 = (t & 15) * 16;
#pragma unroll
    for (int q = 0; q < 4; ++q) {
      float4 v = *(const float4*)(Wm + (size_t)(k0 + kk) * FOUT + n0 + q * 4);
      *(float4*)(&ls[kk * 256 + n0 + q * 4]) = v;
    }
  }
  __syncthreads();
  float v[16];
  unsigned short hh[16], ll[16];
#pragma unroll
  for (int kk = 0; kk < 16; ++kk) {
    v[kk] = ls[kk * 256 + t];
    hh[kk] = f2bf(v[kk]);
    ll[kk] = f2bf(v[kk] - bf2f(hh[kk]));
  }
  unsigned short* oh = WtHi + (size_t)S * 4096 + t * 8;
  unsigned short* ol = WtLo + (size_t)S * 4096 + t * 8;
#pragma unroll
  for (int g = 0; g < 2; ++g) {      // kg 0/1
    ushort4 a, b, c, d;
    a.x = hh[g*8+0]; a.y = hh[g*8+1]; a.z = hh[g*8+2]; a.w = hh[g*8+3];
    b.x = hh[g*8+4]; b.y = hh[g*8+5]; b.z = hh[g*8+6]; b.w = hh[g*8+7];
    c.x = ll[g*8+0]; c.y = ll[g*8+1]; c.z = ll[g*8+2]; c.w = ll[g*8+3];
    d.x = ll[g*8+4]; d.y = ll[g*8+5]; d.z = ll[g*8+6]; d.w = ll[g*8+7];
    *(ushort4*)(oh + g * 2048)     = a;
    *(ushort4*)(oh + g * 2048 + 4) = b;
    *(ushort4*)(ol + g * 2048)     = c;
    *(ushort4*)(ol + g * 2048 + 4) = d;
  }
}

// ---------------- K1: hTt = (x@W)^T via 32x32x16 MFMA, hi/lo split --------
// h = x_hi·W_hi + x_hi·W_lo + x_lo·W_hi  (fp32-class accuracy, fp32 acc).
// Block = 32 i-rows x 256 n (4 waves = n-quadrants). grid 256 (1 block/CU).
// x staged once to LDS hi/lo in the conflict-free B-frag layout; W staged
// per-step via linear global_load_lds (3 bufs, counted vmcnt(4), R11 loop).
// f1/f2 fused from fp32 acc (LDS a-table + shfl + cross-wave reduce).
__global__ __launch_bounds__(256, 1) void k_gemm_h(
    const float* __restrict__ x, const unsigned short* __restrict__ WtHi,
    const unsigned short* __restrict__ WtLo, const float* __restrict__ aG,
    unsigned short* __restrict__ hTt, float* __restrict__ f1,
    float* __restrict__ f2)
{
  __shared__ __align__(16) unsigned short xhi[16384]; // [kg64][i32][b8] 32 KB
  __shared__ __align__(16) unsigned short xlo[16384]; // 32 KB
  __shared__ __align__(16) unsigned short wsh[3][4096]; // [kg2][n256][b8] 8 KB ea
  __shared__ __align__(16) unsigned short wsl[3][4096];
  __shared__ __align__(16) float as2[512];
  __shared__ float f1red[4][32], f2red[4][32];

  const int t  = threadIdx.x;
  const int wv = t >> 6;
  const int l  = t & 63;
  const int lh = l >> 5;
  const int lm = l & 31;
  const int i0 = blockIdx.x * 32;

  if (t < 128) {
    float4 v = *(const float4*)(aG + t * 4);
    *(float4*)(&as2[t * 4]) = v;
  }
  // stage x[i0..i0+32][0..512] -> xhi/xlo
  {
    const int xi = t >> 3;
    const int kb = (t & 7) * 4;
    const float* xrow = x + (size_t)(i0 + xi) * FIN;
    const int kgb = (t & 7) >> 1;
    const int bo  = (t & 1) * 4;
#pragma unroll
    for (int q = 0; q < 16; ++q) {
      float4 v = *(const float4*)(xrow + kb + q * 32);
      ushort4 h4, l4;
      h4.x = f2bf(v.x); l4.x = f2bf(v.x - bf2f(h4.x));
      h4.y = f2bf(v.y); l4.y = f2bf(v.y - bf2f(h4.y));
      h4.z = f2bf(v.z); l4.z = f2bf(v.z - bf2f(h4.z));
      h4.w = f2bf(v.w); l4.w = f2bf(v.w - bf2f(h4.w));
      const int idx = (q * 4 + kgb) * 256 + xi * 8 + bo;
      *(ushort4*)(&xhi[idx]) = h4;
      *(ushort4*)(&xlo[idx]) = l4;
    }
  }

  f32x16 acc0, acc1;
#pragma unroll
  for (int e = 0; e < 16; ++e) { acc0[e] = 0.f; acc1[e] = 0.f; }

#define SB0 __builtin_amdgcn_sched_barrier(0)
#define WSTAGE(B, S)                                                          \
  do {                                                                        \
    const unsigned short* gh_ = WtHi + (size_t)(S) * 4096 + t * 8;            \
    const unsigned short* gl_ = WtLo + (size_t)(S) * 4096 + t * 8;            \
    __builtin_amdgcn_global_load_lds(                                         \
        (const __attribute__((address_space(1))) unsigned int*)gh_,           \
        (__attribute__((address_space(3))) unsigned int*)(&wsh[B][t * 8]), 16, 0, 0); \
    __builtin_amdgcn_global_load_lds(                                         \
        (const __attribute__((address_space(1))) unsigned int*)(gh_ + 2048),  \
        (__attribute__((address_space(3))) unsigned int*)(&wsh[B][2048 + t * 8]), 16, 0, 0); \
    __builtin_amdgcn_global_load_lds(                                         \
        (const __attribute__((address_space(1))) unsigned int*)gl_,           \
        (__attribute__((address_space(3))) unsigned int*)(&wsl[B][t * 8]), 16, 0, 0); \
    __builtin_amdgcn_global_load_lds(                                         \
        (const __attribute__((address_space(1))) unsigned int*)(gl_ + 2048),  \
        (__attribute__((address_space(3))) unsigned int*)(&wsl[B][2048 + t * 8]), 16, 0, 0); \
  } while (0)

#define GTS(S, BUF, DOISSUE, NBUF, VMC)                                       \
  do {                                                                        \
    asm volatile("s_waitcnt vmcnt(" #VMC ")" ::: "memory");                   \
    __builtin_amdgcn_s_barrier();                                             \
    SB0;                                                                      \
    if (DOISSUE) WSTAGE(NBUF, (S) + 2);                                       \
    SB0;                                                                      \
    const int kgb_ = ((S) * 2 + lh) * 512 + lm * 16;                          \
    bf16x8 bh_ = *(const bf16x8*)(((const char*)xhi) + kgb_);                 \
    bf16x8 bl_ = *(const bf16x8*)(((const char*)xlo) + kgb_);                 \
    const int na_ = lh * 4096 + (wv * 64 + lm) * 16;                          \
    bf16x8 ah0_ = *(const bf16x8*)(((const char*)&wsh[BUF][0]) + na_);        \
    bf16x8 al0_ = *(const bf16x8*)(((const char*)&wsl[BUF][0]) + na_);        \
    bf16x8 ah1_ = *(const bf16x8*)(((const char*)&wsh[BUF][0]) + na_ + 512);  \
    bf16x8 al1_ = *(const bf16x8*)(((const char*)&wsl[BUF][0]) + na_ + 512);  \
    acc0 = __builtin_amdgcn_mfma_f32_32x32x16_bf16(ah0_, bh_, acc0, 0, 0, 0); \
    acc1 = __builtin_amdgcn_mfma_f32_32x32x16_bf16(ah1_, bh_, acc1, 0, 0, 0); \
    acc0 = __builtin_amdgcn_mfma_f32_32x32x16_bf16(ah0_, bl_, acc0, 0, 0, 0); \
    acc1 = __builtin_amdgcn_mfma_f32_32x32x16_bf16(ah1_, bl_, acc1, 0, 0, 0); \
    acc0 = __builtin_amdgcn_mfma_f32_32x32x16_bf16(al0_, bh_, acc0, 0, 0, 0); \
    acc1 = __builtin_amdgcn_mfma_f32_32x32x16_bf16(al1_, bh_, acc1, 0, 0, 0); \
  } while (0)

  asm volatile("s_waitcnt vmcnt(0)" ::: "memory");  // x/a loads drained
  SB0;
  WSTAGE(0, 0);
  SB0;
  WSTAGE(1, 1);
  asm volatile("s_waitcnt lgkmcnt(0)" ::: "memory"); // xhi/xlo/as2 ds_writes
  SB0;

#pragma unroll 1
  for (int p = 0; p < 10; ++p) {
    const int s0 = p * 3;
    GTS(s0 + 0, 0, 1, 2, 4);
    GTS(s0 + 1, 1, 1, 0, 4);
    GTS(s0 + 2, 2, 1, 1, 4);
  }
  GTS(30, 0, 0, 2, 4);
  GTS(31, 1, 0, 0, 0);
#undef SB0
#undef WSTAGE
#undef GTS

  // fused f1/f2 from fp32 acc
  float p1 = 0.f, p2 = 0.f;
#pragma unroll
  for (int reg = 0; reg < 16; ++reg) {
    const int nl = (reg & 3) + 8 * (reg >> 2) + 4 * lh;
    p1 += acc0[reg] * as2[wv * 64 + nl]       + acc1[reg] * as2[wv * 64 + 32 + nl];
    p2 += acc0[reg] * as2[256 + wv * 64 + nl] + acc1[reg] * as2[256 + wv * 64 + 32 + nl];
  }
  p1 += __shfl_xor(p1, 32);
  p2 += __shfl_xor(p2, 32);
  if (l < 32) { f1red[wv][l] = p1; f2red[wv][l] = p2; }
  __syncthreads();
  if (t < 32) {
    f1[i0 + t] = f1red[0][t] + f1red[1][t] + f1red[2][t] + f1red[3][t];
    f2[i0 + t] = f2red[0][t] + f2red[1][t] + f2red[2][t] + f2red[3][t];
  }

  // hTt store: j = i0+lm -> hTt[bx*8192 + (lm>>3)*2048 + n*8 + (lm&7)]
  const size_t hb = (size_t)(i0 >> 5) * 8192 + (size_t)(lm >> 3) * 2048 + (lm & 7);
#pragma unroll
  for (int reg = 0; reg < 16; ++reg) {
    const int nl = (reg & 3) + 8 * (reg >> 2) + 4 * lh;
    hTt[hb + (size_t)(wv * 64 + nl) * 8]      = f2bf(acc0[reg]);
    hTt[hb + (size_t)(wv * 64 + 32 + nl) * 8] = f2bf(acc1[reg]);
  }
}

// ---------------- K2: row-max UPPER BOUND m̂_i = lrelu(f1_i + max f2) ------
__global__ __launch_bounds__(1024) void k_bound(
    const float* __restrict__ f1, const float* __restrict__ f2,
    float* __restrict__ mhat)
{
  __shared__ float red[16];
  const int t = threadIdx.x;
  float m = -3.0e38f;
#pragma unroll
  for (int k = 0; k < 8; ++k) m = fmaxf(m, f2[t + k * 1024]);
#pragma unroll
  for (int off = 32; off > 0; off >>= 1) m = fmaxf(m, __shfl_xor(m, off));
  if ((t & 63) == 0) red[t >> 6] = m;
  __syncthreads();
  float fm = red[0];
#pragma unroll
  for (int w = 1; w < 16; ++w) fm = fmaxf(fm, red[w]);
#pragma unroll
  for (int k = 0; k < 8; ++k) {
    int i = t + k * 1024;
    float s = f1[i] + fm;
    mhat[i] = fmaxf(fmaxf(s, ALPHAV * s), MASKF);
  }
}

// ---------------- K3: FUSED adj->bitmask + P-regen + (P@h) MFMA -----------
// (unchanged from R11)
__global__ __launch_bounds__(256, 2) void k_spmm(
    const unsigned short* __restrict__ hTt,
    const int* __restrict__ adj,
    const float* __restrict__ f1, const float* __restrict__ f2,
    const float* __restrict__ mhat,
    float* __restrict__ part, float* __restrict__ rowsumP)
{
  __shared__ __align__(16) unsigned short hbuf[3 * 8192]; // 3 x 16 KB
  __shared__ __align__(16) unsigned int mskL[32 * 129];   // [jt][row]+pad
  __shared__ __align__(16) float f2s[1024];               // pre-scaled by L2E
  const int t  = threadIdx.x;
  const int wv = t >> 6;
  const int l  = t & 63;
  const int lh = l >> 5;
  const int lm = l & 31;
  const int bx = blockIdx.x;
  const int ks = blockIdx.y;
  const int r0 = bx * 128;
  const int lh8 = lh * 8;

  const int rA = r0 + wv * 32 + lm;
  const float nmA   = -mhat[rA] * L2E;
  const float base0 = fmaf(f1[rA], L2E, nmA);
  const float c20   = nmA * (1.f - ALPHAV);
  const float mc0   = fmaf(MASKF, L2E, nmA);

  {
    float4 v = *(const float4*)(f2 + ks * 1024 + t * 4);
    v.x *= L2E; v.y *= L2E; v.z *= L2E; v.w *= L2E;
    *(float4*)(&f2s[t * 4]) = v;
  }

  {
    const int jt = t & 31;
    const int r8 = t >> 5;
    const int* gp = adj + (size_t)(r0 + r8) * NN + ks * 1024 + jt * 32;
#pragma unroll 2
    for (int p = 0; p < 16; ++p) {
      const int* rp = gp + (size_t)p * 8 * NN;
      int4 v[8];
#pragma unroll
      for (int c = 0; c < 8; ++c) v[c] = *(const int4*)(rp + c * 4);
      unsigned int m = 0;
#pragma unroll
      for (int c = 0; c < 8; ++c) {
        m |= (v[c].x > 0 ? 1u : 0u) << (c * 4 + 0);
        m |= (v[c].y > 0 ? 1u : 0u) << (c * 4 + 1);
        m |= (v[c].z > 0 ? 1u : 0u) << (c * 4 + 2);
        m |= (v[c].w > 0 ? 1u : 0u) << (c * 4 + 3);
      }
      mskL[jt * 129 + p * 8 + r8] = m;
    }
  }
  __builtin_amdgcn_sched_barrier(0);

  f32x16 acc[8];
#pragma unroll
  for (int c = 0; c < 8; ++c)
#pragma unroll
    for (int e = 0; e < 16; ++e) acc[c][e] = 0.f;
  float sumP = 0.f;

  const unsigned short* gt0 = hTt + (size_t)ks * 32 * 8192;
  const char* cbase = (const char*)hbuf;
  const int mrow = wv * 32 + lm;

#define SB0 __builtin_amdgcn_sched_barrier(0)
#define STAGE(BUFI, JT)                                                       \
  do {                                                                        \
    const unsigned short* gp_ = gt0 + (size_t)(JT) * 8192 + t * 8;            \
    char* lp_ = ((char*)hbuf) + (BUFI) * 16384 + t * 16;                      \
    _Pragma("unroll")                                                         \
    for (int c = 0; c < 4; ++c) {                                             \
      __builtin_amdgcn_global_load_lds(                                       \
          (const __attribute__((address_space(1))) unsigned int*)(gp_ + c * 2048), \
          (__attribute__((address_space(3))) unsigned int*)(lp_ + c * 4096),  \
          16, 0, 0);                                                          \
    }                                                                         \
  } while (0)

#define REGEN8(AFR, MB, FB)                                                   \
  do {                                                                        \
    float4 fx_ = *(const float4*)(&f2s[FB]);                                  \
    float4 fy_ = *(const float4*)(&f2s[(FB) + 4]);                            \
    float fv_[8] = {fx_.x, fx_.y, fx_.z, fx_.w, fy_.x, fy_.y, fy_.z, fy_.w};  \
    _Pragma("unroll")                                                         \
    for (int b = 0; b < 8; ++b) {                                             \
      float u_ = base0 + fv_[b];                                              \
      float w_ = fmaxf(u_, fmaf(ALPHAV, u_, c20));                            \
      w_ = (((MB) >> b) & 1u) ? w_ : mc0;                                     \
      float p_ = ex2(w_);                                                     \
      sumP += p_;                                                             \
      AFR[b] = (short)f2bf(p_);                                               \
    }                                                                         \
  } while (0)

#define TS(JT, BUF, NBUF, DOISSUE, VMC)                                       \
  do {                                                                        \
    asm volatile("s_waitcnt vmcnt(" #VMC ")" ::: "memory");                   \
    __builtin_amdgcn_s_barrier();                                             \
    SB0;                                                                      \
    if (DOISSUE) STAGE(NBUF, (JT) + 2);                                       \
    SB0;                                                                      \
    const unsigned int m_ = mskL[(JT) * 129 + mrow];                          \
    bf16x8 afr0_, afr1_;                                                      \
    REGEN8(afr0_, m_ >> lh8,        (JT) * 32 + lh8);                         \
    REGEN8(afr1_, m_ >> (16 + lh8), (JT) * 32 + 16 + lh8);                    \
    SB0;                                                                      \
    const char* lb_ = cbase + (BUF) * 16384;                                  \
    const int g0_ = lh * 4096;                                                \
    const int g1_ = (2 + lh) * 4096;                                          \
    const int cb_ = lm * 16;                                                  \
    _Pragma("unroll")                                                         \
    for (int c = 0; c < 8; ++c) {                                             \
      bf16x8 b0_ = *(const bf16x8*)(lb_ + g0_ + c * 512 + cb_);               \
      acc[c] = __builtin_amdgcn_mfma_f32_32x32x16_bf16(afr0_, b0_, acc[c], 0, 0, 0); \
      bf16x8 b1_ = *(const bf16x8*)(lb_ + g1_ + c * 512 + cb_);               \
      acc[c] = __builtin_amdgcn_mfma_f32_32x32x16_bf16(afr1_, b1_, acc[c], 0, 0, 0); \
    }                                                                         \
  } while (0)

  STAGE(0, 0);
  SB0;
  STAGE(1, 1);
  asm volatile("s_waitcnt lgkmcnt(0)" ::: "memory");
  SB0;

#pragma unroll 1
  for (int p = 0; p < 10; ++p) {
    const int s0 = p * 3;
    TS(s0 + 0, 0, 2, 1, 4);
    TS(s0 + 1, 1, 0, 1, 4);
    TS(s0 + 2, 2, 1, 1, 4);
  }
  TS(30, 0, 2, 0, 4);
  TS(31, 1, 0, 0, 0);

#undef SB0
#undef STAGE
#undef REGEN8
#undef TS

  sumP += __shfl_xor(sumP, 32);
  if (lh == 0) rowsumP[(size_t)ks * NN + rA] = sumP;

  float* dst = part + (size_t)ks * NN * FOUT;
  const int rowb = r0 + wv * 32 + 4 * lh;
#pragma unroll
  for (int c = 0; c < 8; ++c) {
    const int col = c * 32 + lm;
#pragma unroll
    for (int reg = 0; reg < 16; ++reg) {
      int row = rowb + (reg & 3) + 8 * (reg >> 2);
      dst[(size_t)row * FOUT + col] = acc[c][reg];
    }
  }
}

// ---------------- K4: sum 8 K-partials + rowsums, normalize ---------------
__global__ __launch_bounds__(256) void k_fin(
    float* __restrict__ outp, const float* __restrict__ part,
    const float* __restrict__ rowsumP)
{
  const int idx4 = blockIdx.x * 256 + threadIdx.x;
  const size_t e = (size_t)idx4 * 4;
  const int i = (int)(e >> 8);
  float rs = 0.f;
#pragma unroll
  for (int p = 0; p < 8; ++p) rs += rowsumP[(size_t)p * NN + i];
  float4 o = {0.f, 0.f, 0.f, 0.f};
#pragma unroll
  for (int p = 0; p < 8; ++p) {
    float4 pv = *(const float4*)(part + (size_t)p * NN * FOUT + e);
    o.x += pv.x; o.y += pv.y; o.z += pv.z; o.w += pv.w;
  }
  float inv = 1.f / rs;
  o.x *= inv; o.y *= inv; o.z *= inv; o.w *= inv;
  *(float4*)(outp + e) = o;
}

extern "C" void kernel_launch(void* const* d_in, const int* in_sizes, int n_in,
                              void* d_out, int out_size, void* d_ws, size_t ws_size,
                              hipStream_t stream)
{
  const float* x  = (const float*)d_in[0];
  const int* adj  = (const int*)d_in[1];
  const float* Wm = (const float*)d_in[2];
  const float* aG = (const float*)d_in[3];
  float* outp = (float*)d_out;

  char* w = (char*)d_ws;
  unsigned short* hTt  = (unsigned short*)(w + 0);           // 4 MB (tiled)
  float* f1            = (float*)(w + 4194304);              // 32 KB
  float* f2            = (float*)(w + 4227072);              // 32 KB
  float* mhat          = (float*)(w + 4259840);              // 32 KB
  float* rowsumP       = (float*)(w + 4292608);              // 256 KB
  unsigned short* WtHi = (unsigned short*)(w + 4554752);     // 256 KB
  unsigned short* WtLo = (unsigned short*)(w + 4816896);     // 256 KB
  float* part          = (float*)(w + 5079040);              // 64 MB (8 slices)

  hipLaunchKernelGGL(k_prep,   dim3(32),    dim3(256),  0, stream, Wm, WtHi, WtLo);
  hipLaunchKernelGGL(k_gemm_h, dim3(256),   dim3(256),  0, stream, x, WtHi, WtLo, aG, hTt, f1, f2);
  hipLaunchKernelGGL(k_bound,  dim3(1),     dim3(1024), 0, stream, f1, f2, mhat);
  hipLaunchKernelGGL(k_spmm,   dim3(64, 8), dim3(256),  0, stream, hTt, adj, f1, f2, mhat, part, rowsumP);
  hipLaunchKernelGGL(k_fin,    dim3(2048),  dim3(256),  0, stream, outp, part, rowsumP);
}